// Round 6
// baseline (432.203 us; speedup 1.0000x reference)
//
#include <hip/hip_runtime.h>
#include <hip/hip_bf16.h>

// Problem constants
#define B_  16
#define N_  2048
#define C_  256
#define BN_ (B_*N_)

typedef __bf16 bf16x8 __attribute__((ext_vector_type(8)));
typedef float  f32x4  __attribute__((ext_vector_type(4)));
typedef int    i32x4  __attribute__((ext_vector_type(4)));

static __device__ __forceinline__ f32x4 MFMA(bf16x8 a, bf16x8 b, f32x4 c){
  return __builtin_amdgcn_mfma_f32_16x16x32_bf16(a, b, c, 0, 0, 0);
}
// f32 -> bf16 bits, round-to-nearest-even
static __device__ __forceinline__ unsigned short f2b(float f){
  unsigned int u = __float_as_uint(f);
  u += 0x7fffu + ((u >> 16) & 1u);
  return (unsigned short)(u >> 16);
}

// ---------------------------------------------------------------------------
// Prep: fold BN scale into bf16 weights, build f32 biases.
// ---------------------------------------------------------------------------
__global__ void prep_kernel(
    const float* __restrict__ w1, const float* __restrict__ w2,
    const float* __restrict__ wqk, const float* __restrict__ wv,
    const float* __restrict__ bv, const float* __restrict__ wt,
    const float* __restrict__ bt,
    const float* __restrict__ g1, const float* __restrict__ b1,
    const float* __restrict__ m1, const float* __restrict__ v1,
    const float* __restrict__ g2, const float* __restrict__ b2,
    const float* __restrict__ m2, const float* __restrict__ v2,
    const float* __restrict__ g3, const float* __restrict__ b3,
    const float* __restrict__ m3, const float* __restrict__ v3,
    unsigned short* __restrict__ w1b, unsigned short* __restrict__ w2b,
    unsigned short* __restrict__ wqkb, unsigned short* __restrict__ wvb,
    unsigned short* __restrict__ wtb,
    float* __restrict__ bias1, float* __restrict__ bias2,
    float* __restrict__ biasv, float* __restrict__ biast)
{
  const int d = blockIdx.x;
  const int c = threadIdx.x;
  const float s1 = g1[d] * rsqrtf(v1[d] + 1e-5f);
  const float s2 = g2[d] * rsqrtf(v2[d] + 1e-5f);
  const float s3 = g3[d] * rsqrtf(v3[d] + 1e-5f);
  if (c < 64) w1b[d*64 + c] = f2b(w1[d*64 + c] * s1);
  w2b[d*256 + c]  = f2b(w2[d*256 + c] * s2);
  wqkb[d*256 + c] = f2b(wqk[d*256 + c]);
  wvb[d*256 + c]  = f2b(wv[d*256 + c]);
  wtb[d*256 + c]  = f2b(wt[d*256 + c] * s3);
  if (c == 0){
    bias1[d] = b1[d] - m1[d]*s1;
    bias2[d] = b2[d] - m2[d]*s2;
    biasv[d] = bv[d];
    biast[d] = bt[d]*s3 + b3[d] - m3[d]*s3;
  }
}

// ---------------------------------------------------------------------------
// Generic "rows x weight^T" GEMM, Mtile=64 rows, all 256 out channels.
// ---------------------------------------------------------------------------
template<int MODE, int K>
__global__ __launch_bounds__(256, 2) void wgemm(
    const void* __restrict__ inp, const unsigned short* __restrict__ wB,
    const float* __restrict__ bias, const float* __restrict__ hf32,
    void* __restrict__ out0, void* __restrict__ out1)
{
  extern __shared__ char smem[];
  unsigned short* Al = (unsigned short*)smem;               // [64][72]
  unsigned short* Bl = (unsigned short*)(smem + 64*72*2);   // [256][72]
  const int tid  = threadIdx.x;
  const int lane = tid & 63;
  const int w    = tid >> 6;
  const int wr   = w >> 1, wc = w & 1;
  const long row0 = (long)blockIdx.x * 64;

  f32x4 acc[2][8];
  #pragma unroll
  for (int m = 0; m < 2; ++m)
    #pragma unroll
    for (int n = 0; n < 8; ++n) acc[m][n] = f32x4{0.f,0.f,0.f,0.f};

  const int KS = K / 64;
  #pragma unroll 1
  for (int s = 0; s < KS; ++s){
    if (s) __syncthreads();
    if constexpr (MODE == 0){
      const float* xin = (const float*)inp;
      #pragma unroll
      for (int t = 0; t < 4; ++t){
        int idx = tid + t*256;              // 1024 chunks of 4 f32
        int r = idx >> 4, c4 = (idx & 15) * 4;
        float4 v = *(const float4*)(xin + (row0 + r)*K + c4);
        unsigned short* dst = &Al[r*72 + c4];
        dst[0]=f2b(v.x); dst[1]=f2b(v.y); dst[2]=f2b(v.z); dst[3]=f2b(v.w);
      }
    } else {
      const unsigned short* bin = (const unsigned short*)inp;
      #pragma unroll
      for (int t = 0; t < 2; ++t){
        int idx = tid + t*256;              // 512 chunks of 8 bf16
        int r = idx >> 3, c8 = (idx & 7) * 8;
        *(i32x4*)&Al[r*72 + c8] = *(const i32x4*)(bin + (row0 + r)*K + s*64 + c8);
      }
    }
    #pragma unroll
    for (int t = 0; t < 8; ++t){
      int idx = tid + t*256;                // 2048 chunks of 8 bf16
      int d = idx >> 3, c8 = (idx & 7) * 8;
      *(i32x4*)&Bl[d*72 + c8] = *(const i32x4*)(wB + d*K + s*64 + c8);
    }
    __syncthreads();
    #pragma unroll
    for (int kk = 0; kk < 2; ++kk){
      bf16x8 a[2], b[8];
      #pragma unroll
      for (int m = 0; m < 2; ++m)
        a[m] = *(const bf16x8*)&Al[(32*wr + 16*m + (lane&15))*72 + kk*32 + (lane>>4)*8];
      #pragma unroll
      for (int n = 0; n < 8; ++n)
        b[n] = *(const bf16x8*)&Bl[(128*wc + 16*n + (lane&15))*72 + kk*32 + (lane>>4)*8];
      #pragma unroll
      for (int m = 0; m < 2; ++m)
        #pragma unroll
        for (int n = 0; n < 8; ++n)
          acc[m][n] = MFMA(a[m], b[n], acc[m][n]);
    }
  }

  // ---- epilogues -------------------------------------------------------
  if constexpr (MODE <= 2){
    unsigned short* obf = (unsigned short*)out0;
    float* of = (float*)out1;
    #pragma unroll
    for (int n = 0; n < 8; ++n){
      int col = 128*wc + 16*n + (lane&15);
      float bs = 0.f;
      if constexpr (MODE != 2) bs = bias[col];
      #pragma unroll
      for (int m = 0; m < 2; ++m){
        int rl = 32*wr + 16*m + (lane>>4)*4;
        #pragma unroll
        for (int r = 0; r < 4; ++r){
          float v = acc[m][n][r] + bs;
          if constexpr (MODE == 0 || MODE == 1) v = fmaxf(v, 0.f);
          obf[(row0 + rl + r)*256 + col] = f2b(v);
          if constexpr (MODE == 1) of[(row0 + rl + r)*256 + col] = v;
        }
      }
    }
  } else if constexpr (MODE == 3){
    __syncthreads();
    unsigned short* Vl = (unsigned short*)smem;   // [64][264]
    #pragma unroll
    for (int n = 0; n < 8; ++n){
      int col = 128*wc + 16*n + (lane&15);
      float bs = bias[col];
      #pragma unroll
      for (int m = 0; m < 2; ++m){
        int rl = 32*wr + 16*m + (lane>>4)*4;
        #pragma unroll
        for (int r = 0; r < 4; ++r)
          Vl[(rl + r)*264 + col] = f2b(acc[m][n][r] + bs);
      }
    }
    __syncthreads();
    long b = row0 >> 11;
    int  n0 = (int)(row0 & 2047);
    unsigned short* vt = (unsigned short*)out0 + b*(256L*2048);
    #pragma unroll 1
    for (int cc = 0; cc < 64; ++cc){
      int c = 64*w + cc;
      vt[(long)c*2048 + n0 + lane] = Vl[lane*264 + c];
    }
  } else {  // MODE 4
    __syncthreads();
    float* Ol = (float*)smem;                    // [64][265]
    #pragma unroll
    for (int n = 0; n < 8; ++n){
      int col = 128*wc + 16*n + (lane&15);
      float bs = bias[col];
      #pragma unroll
      for (int m = 0; m < 2; ++m){
        int rl = 32*wr + 16*m + (lane>>4)*4;
        #pragma unroll
        for (int r = 0; r < 4; ++r){
          float t = fmaxf(acc[m][n][r] + bs, 0.f);
          float h = hf32[(row0 + rl + r)*256 + col];
          Ol[(rl + r)*265 + col] = h + t;
        }
      }
    }
    __syncthreads();
    long b = row0 >> 11;
    int  n0 = (int)(row0 & 2047);
    float* op = (float*)out0 + b*(256L*2048);
    #pragma unroll 1
    for (int cc = 0; cc < 64; ++cc){
      int c = 64*w + cc;
      op[(long)c*2048 + n0 + lane] = Ol[lane*265 + c];
    }
  }
}

// ---------------------------------------------------------------------------
// Pass 1: per-row online softmax stats over E[i,j] = q_i . q_j
// Swapped-operand MFMA (i on D-column, j lane-local) + SPLIT jf HALVES:
// e[2][4] accumulators (32 VGPR) with the pure-VALU online update after each
// half — peak live set ~80 VGPR, no spill (round 2-4 had 12.5MB scratch
// writes / 1% occupancy from spilling e[4][4]+dbuf). No explicit prefetch:
// 4 waves/SIMD of TLP hide the load latency instead.
// ---------------------------------------------------------------------------
__global__ __launch_bounds__(256, 4) void pass1_kernel(
    const unsigned short* __restrict__ q,
    float* __restrict__ rowm, float* __restrict__ rowl)
{
  __shared__ unsigned short qi[64*264];
  __shared__ float smm[4][64], sml[4][64];
  const int tid = threadIdx.x, lane = tid & 63, w = tid >> 6;
  const int l15 = lane & 15, hi = lane >> 4;
  const int lin = blockIdx.y * 32 + blockIdx.x;
  const int swz = (lin & 7) * 64 + (lin >> 3);   // XCD k -> 64 contiguous blocks
  const int b  = swz >> 5;
  const int i0 = (swz & 31) * 64;
  const unsigned short* qb = q + (long)b*N_*C_;

  #pragma unroll
  for (int t = 0; t < 8; ++t){
    int idx = tid + t*256;                 // 2048 chunks of 8 bf16
    int r = idx >> 5, c8 = (idx & 31) * 8;
    *(i32x4*)&qi[r*264 + c8] = *(const i32x4*)(qb + (long)(i0 + r)*256 + c8);
  }
  __syncthreads();

  // lane-local stats for i = 16*ii + l15, partial over this lane-group's j's
  float mloc[4], lloc[4];
  #pragma unroll
  for (int ii = 0; ii < 4; ++ii){ mloc[ii] = -3e38f; lloc[ii] = 0.f; }

  #pragma unroll 1
  for (int js = 0; js < 8; ++js){
    const int j0 = js*256 + 64*w;
    #pragma unroll
    for (int h = 0; h < 2; ++h){
      f32x4 e[2][4];                        // [jf-half][ii]
      #pragma unroll
      for (int jf = 0; jf < 2; ++jf)
        #pragma unroll
        for (int ii = 0; ii < 4; ++ii) e[jf][ii] = f32x4{0.f,0.f,0.f,0.f};

      #pragma unroll
      for (int kk = 0; kk < 8; ++kk){
        bf16x8 aa[4], bb[2];
        #pragma unroll
        for (int ii = 0; ii < 4; ++ii)
          aa[ii] = *(const bf16x8*)&qi[(16*ii + l15)*264 + kk*32 + hi*8];
        #pragma unroll
        for (int jf = 0; jf < 2; ++jf)
          bb[jf] = *(const bf16x8*)(qb + (long)(j0 + 16*(2*h + jf) + l15)*256 + kk*32 + hi*8);
        #pragma unroll
        for (int jf = 0; jf < 2; ++jf)
          #pragma unroll
          for (int ii = 0; ii < 4; ++ii)
            e[jf][ii] = MFMA(bb[jf], aa[ii], e[jf][ii]);
      }

      // pure-VALU online update: lane's 8 j-values (this half) per i-column
      #pragma unroll
      for (int ii = 0; ii < 4; ++ii){
        float tm = fmaxf(fmaxf(fmaxf(e[0][ii][0], e[0][ii][1]), fmaxf(e[0][ii][2], e[0][ii][3])),
                         fmaxf(fmaxf(e[1][ii][0], e[1][ii][1]), fmaxf(e[1][ii][2], e[1][ii][3])));
        float mn = fmaxf(mloc[ii], tm);
        float p = 0.f;
        #pragma unroll
        for (int jf = 0; jf < 2; ++jf)
          #pragma unroll
          for (int r = 0; r < 4; ++r)
            p += __expf(e[jf][ii][r] - mn);
        lloc[ii] = lloc[ii]*__expf(mloc[ii] - mn) + p;
        mloc[ii] = mn;
      }
    }
  }

  // merge across the 4 lane-groups (they hold disjoint j-sets for same i)
  #pragma unroll
  for (int ii = 0; ii < 4; ++ii){
    float m0 = mloc[ii], l0 = lloc[ii];
    float mo = __shfl_xor(m0, 16), lo = __shfl_xor(l0, 16);
    float mn = fmaxf(m0, mo);
    l0 = l0*__expf(m0 - mn) + lo*__expf(mo - mn); m0 = mn;
    mo = __shfl_xor(m0, 32); lo = __shfl_xor(l0, 32);
    mn = fmaxf(m0, mo);
    l0 = l0*__expf(m0 - mn) + lo*__expf(mo - mn); m0 = mn;
    if (lane < 16){
      smm[w][16*ii + l15] = m0;
      sml[w][16*ii + l15] = l0;
    }
  }
  __syncthreads();
  // cross-wave merge (each wave covered a disjoint 1/4 of j)
  if (tid < 64){
    float m0 = smm[0][tid], m1 = smm[1][tid], m2 = smm[2][tid], m3 = smm[3][tid];
    float M = fmaxf(fmaxf(m0, m1), fmaxf(m2, m3));
    float L = sml[0][tid]*__expf(m0 - M) + sml[1][tid]*__expf(m1 - M)
            + sml[2][tid]*__expf(m2 - M) + sml[3][tid]*__expf(m3 - M);
    rowm[(long)b*N_ + i0 + tid] = M;
    rowl[(long)b*N_ + i0 + tid] = L;
  }
}

// ---------------------------------------------------------------------------
// Pass 2, fat/thin restructure (round-3 form, proven 149 us):
//   per is-step: FAT = [ E'(is) MFMA+loads ; PV(is-1) MFMA+loads ; exp(is)->regs ]
//                -> barrier -> THIN = [ P' writes to pl ] -> barrier
// ---------------------------------------------------------------------------
__global__ __launch_bounds__(256, 2) void pass2_kernel(
    const unsigned short* __restrict__ q, const unsigned short* __restrict__ vT,
    const float* __restrict__ rowm, const float* __restrict__ rowl,
    const float* __restrict__ hf, unsigned short* __restrict__ dbf)
{
  extern __shared__ char smem[];
  unsigned short* qj = (unsigned short*)smem;   // [64][264]
  unsigned short* pl = qj + 64*264;             // [64][264]
  float* colsum = (float*)(pl + 64*264);        // [64]
  const int tid = threadIdx.x, lane = tid & 63, w = tid >> 6;
  const int lin = blockIdx.y * 32 + blockIdx.x;
  const int swz = (lin & 7) * 64 + (lin >> 3);  // XCD k -> 64 contiguous blocks
  const int b  = swz >> 5;
  const int j0 = (swz & 31) * 64;
  const unsigned short* qb = q  + (long)b*N_*C_;
  const unsigned short* vb = vT + (long)b*N_*C_;
  const float* mrow = rowm + (long)b*N_;
  const float* lrow = rowl + (long)b*N_;

  #pragma unroll
  for (int t = 0; t < 8; ++t){
    int idx = tid + t*256;
    int r = idx >> 5, c8 = (idx & 31) * 8;
    *(i32x4*)&qj[r*264 + c8] = *(const i32x4*)(qb + (long)(j0 + r)*256 + c8);
  }
  if (tid < 64) colsum[tid] = 0.f;
  __syncthreads();

  float cs[4][4];
  #pragma unroll
  for (int a = 0; a < 4; ++a)
    #pragma unroll
    for (int r = 0; r < 4; ++r) cs[a][r] = 0.f;
  f32x4 nm[4][4];
  #pragma unroll
  for (int a = 0; a < 4; ++a)
    #pragma unroll
    for (int c = 0; c < 4; ++c) nm[a][c] = f32x4{0.f,0.f,0.f,0.f};

  unsigned int pk[4][4][2];   // packed P' bf16 pairs [jf][f][r-pair]

  #pragma unroll 1
  for (int is = 0; is < 8; ++is){
    const int i0 = is * 256;
    const int iw = i0 + 64*w;       // this wave's i-slice

    // hoist m/l loads (independent of MFMA)
    float mi[4], ri[4];
    #pragma unroll
    for (int f = 0; f < 4; ++f){
      int ig = iw + 16*f + (lane&15);
      mi[f] = mrow[ig];
      ri[f] = __builtin_amdgcn_rcpf(lrow[ig]);
    }

    // ---- E'(is) ----
    f32x4 e[4][4];                  // [jf][if]
    #pragma unroll
    for (int a = 0; a < 4; ++a)
      #pragma unroll
      for (int f = 0; f < 4; ++f) e[a][f] = f32x4{0.f,0.f,0.f,0.f};
    #pragma unroll
    for (int kk = 0; kk < 8; ++kk){
      bf16x8 a[4], bb[4];
      #pragma unroll
      for (int jf = 0; jf < 4; ++jf)
        a[jf] = *(const bf16x8*)&qj[(16*jf + (lane&15))*264 + kk*32 + (lane>>4)*8];
      #pragma unroll
      for (int f = 0; f < 4; ++f)
        bb[f] = *(const bf16x8*)(qb + (long)(iw + 16*f + (lane&15))*256 + kk*32 + (lane>>4)*8);
      #pragma unroll
      for (int jf = 0; jf < 4; ++jf)
        #pragma unroll
        for (int f = 0; f < 4; ++f)
          e[jf][f] = MFMA(a[jf], bb[f], e[jf][f]);
    }

    // ---- PV(is-1): reads pl written in previous thin phase ----
    if (is > 0){
      const int ip = i0 - 256;
      #pragma unroll
      for (int kc = 0; kc < 8; ++kc){
        bf16x8 pa[4], vv[4];
        #pragma unroll
        for (int jf = 0; jf < 4; ++jf)
          pa[jf] = *(const bf16x8*)&pl[(16*jf + (lane&15))*264 + kc*32 + (lane>>4)*8];
        #pragma unroll
        for (int cf = 0; cf < 4; ++cf)
          vv[cf] = *(const bf16x8*)(vb + (long)(64*w + 16*cf + (lane&15))*2048 + ip + kc*32 + (lane>>4)*8);
        #pragma unroll
        for (int jf = 0; jf < 4; ++jf)
          #pragma unroll
          for (int cf = 0; cf < 4; ++cf)
            nm[jf][cf] = MFMA(pa[jf], vv[cf], nm[jf][cf]);
      }
    }

    // ---- exp(is) -> packed regs (VALU; co-schedules with PV MFMA) ----
    #pragma unroll
    for (int f = 0; f < 4; ++f){
      #pragma unroll
      for (int jf = 0; jf < 4; ++jf){
        #pragma unroll
        for (int rp = 0; rp < 2; ++rp){
          float p0 = __expf(e[jf][f][2*rp]   - mi[f]) * ri[f];
          float p1 = __expf(e[jf][f][2*rp+1] - mi[f]) * ri[f];
          cs[jf][2*rp]   += p0;
          cs[jf][2*rp+1] += p1;
          pk[jf][f][rp] = (unsigned int)f2b(p0) | ((unsigned int)f2b(p1) << 16);
        }
      }
    }

    __syncthreads();   // all PV(is-1) reads of pl done
    // ---- THIN: write P'(is) ----
    #pragma unroll
    for (int jf = 0; jf < 4; ++jf)
      #pragma unroll
      for (int f = 0; f < 4; ++f)
        #pragma unroll
        for (int rp = 0; rp < 2; ++rp){
          unsigned int v = pk[jf][f][rp];
          int col = 64*w + 16*f + (lane&15);
          pl[(16*jf + (lane>>4)*4 + 2*rp)*264 + col]     = (unsigned short)v;
          pl[(16*jf + (lane>>4)*4 + 2*rp+1)*264 + col]   = (unsigned short)(v >> 16);
        }
    __syncthreads();
  }

  // ---- PV(7) tail ----
  {
    const int ip = 7 * 256;
    #pragma unroll
    for (int kc = 0; kc < 8; ++kc){
      bf16x8 pa[4], vv[4];
      #pragma unroll
      for (int jf = 0; jf < 4; ++jf)
        pa[jf] = *(const bf16x8*)&pl[(16*jf + (lane&15))*264 + kc*32 + (lane>>4)*8];
      #pragma unroll
      for (int cf = 0; cf < 4; ++cf)
        vv[cf] = *(const bf16x8*)(vb + (long)(64*w + 16*cf + (lane&15))*2048 + ip + kc*32 + (lane>>4)*8);
      #pragma unroll
      for (int jf = 0; jf < 4; ++jf)
        #pragma unroll
        for (int cf = 0; cf < 4; ++cf)
          nm[jf][cf] = MFMA(pa[jf], vv[cf], nm[jf][cf]);
    }
  }

  // colsum: reduce across the 16-lane column group, then across waves via LDS atomics
  #pragma unroll
  for (int jf = 0; jf < 4; ++jf)
    #pragma unroll
    for (int r = 0; r < 4; ++r){
      float v = cs[jf][r];
      v += __shfl_xor(v, 1); v += __shfl_xor(v, 2);
      v += __shfl_xor(v, 4); v += __shfl_xor(v, 8);
      if ((lane & 15) == 0) atomicAdd(&colsum[16*jf + (lane>>4)*4 + r], v);
    }
  __syncthreads();

  #pragma unroll
  for (int jf = 0; jf < 4; ++jf)
    #pragma unroll
    for (int r = 0; r < 4; ++r){
      int jl = 16*jf + (lane>>4)*4 + r;
      float rcs = __builtin_amdgcn_rcpf(1e-9f + colsum[jl]);
      long rowg = (long)b*N_ + j0 + jl;
      #pragma unroll
      for (int cf = 0; cf < 4; ++cf){
        int c = 64*w + 16*cf + (lane&15);
        float xr = nm[jf][cf][r] * rcs;
        float d = hf[rowg*256 + c] - xr;
        dbf[rowg*256 + c] = f2b(d);
      }
    }
}

// ---------------------------------------------------------------------------
extern "C" void kernel_launch(void* const* d_in, const int* in_sizes, int n_in,
                              void* d_out, int out_size, void* d_ws, size_t ws_size,
                              hipStream_t stream)
{
  const float* x   = (const float*)d_in[0];
  const float* w1  = (const float*)d_in[1];
  const float* w2  = (const float*)d_in[2];
  const float* wqk = (const float*)d_in[3];
  const float* wv  = (const float*)d_in[4];
  const float* bv  = (const float*)d_in[5];
  const float* wt  = (const float*)d_in[6];
  const float* bt  = (const float*)d_in[7];
  const float* g1 = (const float*)d_in[8],  *b1 = (const float*)d_in[9];
  const float* m1 = (const float*)d_in[10], *v1 = (const float*)d_in[11];
  const float* g2 = (const float*)d_in[12], *b2 = (const float*)d_in[13];
  const float* m2 = (const float*)d_in[14], *v2 = (const float*)d_in[15];
  const float* g3 = (const float*)d_in[16], *b3 = (const float*)d_in[17];
  const float* m3 = (const float*)d_in[18], *v3 = (const float*)d_in[19];

  char* ws = (char*)d_ws;
  size_t off = 0;
  auto alloc = [&](size_t bytes)->char*{
    char* p = ws + off; off += (bytes + 255) & ~(size_t)255; return p;
  };
  unsigned short* w1b  = (unsigned short*)alloc(256*64*2);
  unsigned short* w2b  = (unsigned short*)alloc(256*256*2);
  unsigned short* wqkb = (unsigned short*)alloc(256*256*2);
  unsigned short* wvb  = (unsigned short*)alloc(256*256*2);
  unsigned short* wtb  = (unsigned short*)alloc(256*256*2);
  float* bias1 = (float*)alloc(256*4);
  float* bias2 = (float*)alloc(256*4);
  float* biasv = (float*)alloc(256*4);
  float* biast = (float*)alloc(256*4);
  unsigned short* h1_bf = (unsigned short*)alloc((size_t)BN_*C_*2);
  float*          h_f32 = (float*)alloc((size_t)BN_*C_*4);
  unsigned short* h_bf  = (unsigned short*)alloc((size_t)BN_*C_*2);
  unsigned short* q_bf  = (unsigned short*)alloc((size_t)BN_*C_*2);
  unsigned short* vT_bf = (unsigned short*)alloc((size_t)BN_*C_*2);
  float* rowm = (float*)alloc((size_t)BN_*4);
  float* rowl = (float*)alloc((size_t)BN_*4);
  unsigned short* d_bf  = (unsigned short*)alloc((size_t)BN_*C_*2);
  (void)ws_size; (void)in_sizes; (void)n_in; (void)out_size;

  hipFuncSetAttribute((const void*)&pass2_kernel,
                      hipFuncAttributeMaxDynamicSharedMemorySize, 67840);
  hipFuncSetAttribute((const void*)&wgemm<4,256>,
                      hipFuncAttributeMaxDynamicSharedMemorySize, 67840);

  prep_kernel<<<256, 256, 0, stream>>>(w1, w2, wqk, wv, bv, wt, bt,
      g1,b1,m1,v1, g2,b2,m2,v2, g3,b3,m3,v3,
      w1b, w2b, wqkb, wvb, wtb, bias1, bias2, biasv, biast);

  wgemm<0,64><<<512, 256, 46080, stream>>>(x, w1b, bias1, nullptr, h1_bf, nullptr);
  wgemm<1,256><<<512, 256, 46080, stream>>>(h1_bf, w2b, bias2, nullptr, h_bf, h_f32);
  wgemm<2,256><<<512, 256, 46080, stream>>>(h_bf, wqkb, nullptr, nullptr, q_bf, nullptr);
  wgemm<3,256><<<512, 256, 46080, stream>>>(h_bf, wvb, biasv, nullptr, vT_bf, nullptr);

  pass1_kernel<<<dim3(32,16), 256, 0, stream>>>(q_bf, rowm, rowl);
  pass2_kernel<<<dim3(32,16), 256, 67840, stream>>>(q_bf, vT_bf, rowm, rowl, h_f32, d_bf);

  wgemm<4,256><<<512, 256, 67840, stream>>>(d_bf, wtb, biast, h_f32, d_out, nullptr);
}

// Round 7
// 360.658 us; speedup vs baseline: 1.1984x; 1.1984x over previous
//
#include <hip/hip_runtime.h>
#include <hip/hip_bf16.h>

// Problem constants
#define B_  16
#define N_  2048
#define C_  256
#define BN_ (B_*N_)

typedef __bf16 bf16x8 __attribute__((ext_vector_type(8)));
typedef float  f32x4  __attribute__((ext_vector_type(4)));
typedef int    i32x4  __attribute__((ext_vector_type(4)));

static __device__ __forceinline__ f32x4 MFMA(bf16x8 a, bf16x8 b, f32x4 c){
  return __builtin_amdgcn_mfma_f32_16x16x32_bf16(a, b, c, 0, 0, 0);
}
// f32 -> bf16 bits, round-to-nearest-even
static __device__ __forceinline__ unsigned short f2b(float f){
  unsigned int u = __float_as_uint(f);
  u += 0x7fffu + ((u >> 16) & 1u);
  return (unsigned short)(u >> 16);
}

// ---------------------------------------------------------------------------
// Prep: fold BN scale into bf16 weights, build f32 biases.
// ---------------------------------------------------------------------------
__global__ void prep_kernel(
    const float* __restrict__ w1, const float* __restrict__ w2,
    const float* __restrict__ wqk, const float* __restrict__ wv,
    const float* __restrict__ bv, const float* __restrict__ wt,
    const float* __restrict__ bt,
    const float* __restrict__ g1, const float* __restrict__ b1,
    const float* __restrict__ m1, const float* __restrict__ v1,
    const float* __restrict__ g2, const float* __restrict__ b2,
    const float* __restrict__ m2, const float* __restrict__ v2,
    const float* __restrict__ g3, const float* __restrict__ b3,
    const float* __restrict__ m3, const float* __restrict__ v3,
    unsigned short* __restrict__ w1b, unsigned short* __restrict__ w2b,
    unsigned short* __restrict__ wqkb, unsigned short* __restrict__ wvb,
    unsigned short* __restrict__ wtb,
    float* __restrict__ bias1, float* __restrict__ bias2,
    float* __restrict__ biasv, float* __restrict__ biast)
{
  const int d = blockIdx.x;
  const int c = threadIdx.x;
  const float s1 = g1[d] * rsqrtf(v1[d] + 1e-5f);
  const float s2 = g2[d] * rsqrtf(v2[d] + 1e-5f);
  const float s3 = g3[d] * rsqrtf(v3[d] + 1e-5f);
  if (c < 64) w1b[d*64 + c] = f2b(w1[d*64 + c] * s1);
  w2b[d*256 + c]  = f2b(w2[d*256 + c] * s2);
  wqkb[d*256 + c] = f2b(wqk[d*256 + c]);
  wvb[d*256 + c]  = f2b(wv[d*256 + c]);
  wtb[d*256 + c]  = f2b(wt[d*256 + c] * s3);
  if (c == 0){
    bias1[d] = b1[d] - m1[d]*s1;
    bias2[d] = b2[d] - m2[d]*s2;
    biasv[d] = bv[d];
    biast[d] = bt[d]*s3 + b3[d] - m3[d]*s3;
  }
}

// ---------------------------------------------------------------------------
// Generic "rows x weight^T" GEMM, Mtile=64 rows, all 256 out channels.
// MODE 2 additionally emits rowm[i] = sum_c q[i,c]^2 (= E[i,i], the softmax
// shift) via out1 — each block owns all 256 cols of its 64 rows, so the
// row sum-of-squares is block-local (shfl + LDS atomic, no global sync).
// ---------------------------------------------------------------------------
template<int MODE, int K>
__global__ __launch_bounds__(256, 2) void wgemm(
    const void* __restrict__ inp, const unsigned short* __restrict__ wB,
    const float* __restrict__ bias, const float* __restrict__ hf32,
    void* __restrict__ out0, void* __restrict__ out1)
{
  extern __shared__ char smem[];
  unsigned short* Al = (unsigned short*)smem;               // [64][72]
  unsigned short* Bl = (unsigned short*)(smem + 64*72*2);   // [256][72]
  const int tid  = threadIdx.x;
  const int lane = tid & 63;
  const int w    = tid >> 6;
  const int wr   = w >> 1, wc = w & 1;
  const long row0 = (long)blockIdx.x * 64;

  f32x4 acc[2][8];
  #pragma unroll
  for (int m = 0; m < 2; ++m)
    #pragma unroll
    for (int n = 0; n < 8; ++n) acc[m][n] = f32x4{0.f,0.f,0.f,0.f};

  const int KS = K / 64;
  #pragma unroll 1
  for (int s = 0; s < KS; ++s){
    if (s) __syncthreads();
    if constexpr (MODE == 0){
      const float* xin = (const float*)inp;
      #pragma unroll
      for (int t = 0; t < 4; ++t){
        int idx = tid + t*256;              // 1024 chunks of 4 f32
        int r = idx >> 4, c4 = (idx & 15) * 4;
        float4 v = *(const float4*)(xin + (row0 + r)*K + c4);
        unsigned short* dst = &Al[r*72 + c4];
        dst[0]=f2b(v.x); dst[1]=f2b(v.y); dst[2]=f2b(v.z); dst[3]=f2b(v.w);
      }
    } else {
      const unsigned short* bin = (const unsigned short*)inp;
      #pragma unroll
      for (int t = 0; t < 2; ++t){
        int idx = tid + t*256;              // 512 chunks of 8 bf16
        int r = idx >> 3, c8 = (idx & 7) * 8;
        *(i32x4*)&Al[r*72 + c8] = *(const i32x4*)(bin + (row0 + r)*K + s*64 + c8);
      }
    }
    #pragma unroll
    for (int t = 0; t < 8; ++t){
      int idx = tid + t*256;                // 2048 chunks of 8 bf16
      int d = idx >> 3, c8 = (idx & 7) * 8;
      *(i32x4*)&Bl[d*72 + c8] = *(const i32x4*)(wB + d*K + s*64 + c8);
    }
    __syncthreads();
    #pragma unroll
    for (int kk = 0; kk < 2; ++kk){
      bf16x8 a[2], b[8];
      #pragma unroll
      for (int m = 0; m < 2; ++m)
        a[m] = *(const bf16x8*)&Al[(32*wr + 16*m + (lane&15))*72 + kk*32 + (lane>>4)*8];
      #pragma unroll
      for (int n = 0; n < 8; ++n)
        b[n] = *(const bf16x8*)&Bl[(128*wc + 16*n + (lane&15))*72 + kk*32 + (lane>>4)*8];
      #pragma unroll
      for (int m = 0; m < 2; ++m)
        #pragma unroll
        for (int n = 0; n < 8; ++n)
          acc[m][n] = MFMA(a[m], b[n], acc[m][n]);
    }
  }

  // ---- epilogues -------------------------------------------------------
  if constexpr (MODE <= 2){
    unsigned short* obf = (unsigned short*)out0;
    float* of = (float*)out1;
    float sq[2][4];
    #pragma unroll
    for (int m = 0; m < 2; ++m)
      #pragma unroll
      for (int r = 0; r < 4; ++r) sq[m][r] = 0.f;
    #pragma unroll
    for (int n = 0; n < 8; ++n){
      int col = 128*wc + 16*n + (lane&15);
      float bs = 0.f;
      if constexpr (MODE != 2) bs = bias[col];
      #pragma unroll
      for (int m = 0; m < 2; ++m){
        int rl = 32*wr + 16*m + (lane>>4)*4;
        #pragma unroll
        for (int r = 0; r < 4; ++r){
          float v = acc[m][n][r] + bs;
          if constexpr (MODE == 0 || MODE == 1) v = fmaxf(v, 0.f);
          obf[(row0 + rl + r)*256 + col] = f2b(v);
          if constexpr (MODE == 1) of[(row0 + rl + r)*256 + col] = v;
          if constexpr (MODE == 2) sq[m][r] += v*v;
        }
      }
    }
    if constexpr (MODE == 2){
      // reduce sq over the 16 cols of this lane-group, then cross-wave in LDS
      #pragma unroll
      for (int m = 0; m < 2; ++m)
        #pragma unroll
        for (int r = 0; r < 4; ++r){
          float s = sq[m][r];
          s += __shfl_xor(s, 1); s += __shfl_xor(s, 2);
          s += __shfl_xor(s, 4); s += __shfl_xor(s, 8);
          sq[m][r] = s;
        }
      __syncthreads();
      float* ssq = (float*)smem;
      if (tid < 64) ssq[tid] = 0.f;
      __syncthreads();
      if ((lane & 15) == 0){
        #pragma unroll
        for (int m = 0; m < 2; ++m)
          #pragma unroll
          for (int r = 0; r < 4; ++r)
            atomicAdd(&ssq[32*wr + 16*m + (lane>>4)*4 + r], sq[m][r]);
      }
      __syncthreads();
      if (tid < 64) ((float*)out1)[row0 + tid] = ssq[tid];
    }
  } else if constexpr (MODE == 3){
    __syncthreads();
    unsigned short* Vl = (unsigned short*)smem;   // [64][264]
    #pragma unroll
    for (int n = 0; n < 8; ++n){
      int col = 128*wc + 16*n + (lane&15);
      float bs = bias[col];
      #pragma unroll
      for (int m = 0; m < 2; ++m){
        int rl = 32*wr + 16*m + (lane>>4)*4;
        #pragma unroll
        for (int r = 0; r < 4; ++r)
          Vl[(rl + r)*264 + col] = f2b(acc[m][n][r] + bs);
      }
    }
    __syncthreads();
    long b = row0 >> 11;
    int  n0 = (int)(row0 & 2047);
    unsigned short* vt = (unsigned short*)out0 + b*(256L*2048);
    #pragma unroll 1
    for (int cc = 0; cc < 64; ++cc){
      int c = 64*w + cc;
      vt[(long)c*2048 + n0 + lane] = Vl[lane*264 + c];
    }
  } else {  // MODE 4
    __syncthreads();
    float* Ol = (float*)smem;                    // [64][265]
    #pragma unroll
    for (int n = 0; n < 8; ++n){
      int col = 128*wc + 16*n + (lane&15);
      float bs = bias[col];
      #pragma unroll
      for (int m = 0; m < 2; ++m){
        int rl = 32*wr + 16*m + (lane>>4)*4;
        #pragma unroll
        for (int r = 0; r < 4; ++r){
          float t = fmaxf(acc[m][n][r] + bs, 0.f);
          float h = hf32[(row0 + rl + r)*256 + col];
          Ol[(rl + r)*265 + col] = h + t;
        }
      }
    }
    __syncthreads();
    long b = row0 >> 11;
    int  n0 = (int)(row0 & 2047);
    float* op = (float*)out0 + b*(256L*2048);
    #pragma unroll 1
    for (int cc = 0; cc < 64; ++cc){
      int c = 64*w + cc;
      op[(long)c*2048 + n0 + lane] = Ol[lane*265 + c];
    }
  }
}

// ---------------------------------------------------------------------------
// Pass 1 (l-only): rowl[i] = sum_j exp(E[i,j] - rowm[i]), rowm precomputed
// by wgemm<2> (= ||q_i||^2, a valid softmax shift: <= row max by the diagonal,
// and row max - m <= M^2/4 ~ 26 by Cauchy-Schwarz -> exp/l fit f32 easily).
// Swapped-operand MFMA: i lives on D-col (lane&15) -> per-lane accumulation
// is pure VALU. kk loop is NOT unrolled (#pragma unroll 1) so the compiler
// cannot hoist all fragment loads -> no register spill (rounds 2-6's killer:
// 12-62MB scratch writes, 258MB reloads, <1% occupancy).
// ---------------------------------------------------------------------------
__global__ __launch_bounds__(256, 2) void pass1_kernel(
    const unsigned short* __restrict__ q,
    const float* __restrict__ rowm, float* __restrict__ rowl)
{
  __shared__ unsigned short qi[64*264];
  __shared__ float sll[4][64];
  const int tid = threadIdx.x, lane = tid & 63, w = tid >> 6;
  const int l15 = lane & 15, hi = lane >> 4;
  const int lin = blockIdx.y * 32 + blockIdx.x;
  const int swz = (lin & 7) * 64 + (lin >> 3);   // XCD k -> 64 contiguous blocks
  const int b  = swz >> 5;
  const int i0 = (swz & 31) * 64;
  const unsigned short* qb = q + (long)b*N_*C_;

  #pragma unroll
  for (int t = 0; t < 8; ++t){
    int idx = tid + t*256;                 // 2048 chunks of 8 bf16
    int r = idx >> 5, c8 = (idx & 31) * 8;
    *(i32x4*)&qi[r*264 + c8] = *(const i32x4*)(qb + (long)(i0 + r)*256 + c8);
  }

  float mi[4], lacc[4];
  #pragma unroll
  for (int ii = 0; ii < 4; ++ii){
    mi[ii] = rowm[(long)b*N_ + i0 + 16*ii + l15];
    lacc[ii] = 0.f;
  }
  __syncthreads();

  #pragma unroll 1
  for (int js = 0; js < 8; ++js){
    const int j0 = js*256 + 64*w;
    #pragma unroll
    for (int h = 0; h < 2; ++h){
      f32x4 e[2][4];                        // [jf][ii]
      #pragma unroll
      for (int jf = 0; jf < 2; ++jf)
        #pragma unroll
        for (int ii = 0; ii < 4; ++ii) e[jf][ii] = f32x4{0.f,0.f,0.f,0.f};

      #pragma unroll 1
      for (int kk = 0; kk < 8; ++kk){
        bf16x8 aa[4], bb[2];
        #pragma unroll
        for (int ii = 0; ii < 4; ++ii)
          aa[ii] = *(const bf16x8*)&qi[(16*ii + l15)*264 + kk*32 + hi*8];
        #pragma unroll
        for (int jf = 0; jf < 2; ++jf)
          bb[jf] = *(const bf16x8*)(qb + (long)(j0 + 16*(2*h + jf) + l15)*256 + kk*32 + hi*8);
        #pragma unroll
        for (int jf = 0; jf < 2; ++jf)
          #pragma unroll
          for (int ii = 0; ii < 4; ++ii)
            e[jf][ii] = MFMA(bb[jf], aa[ii], e[jf][ii]);
      }

      #pragma unroll
      for (int ii = 0; ii < 4; ++ii){
        float p = 0.f;
        #pragma unroll
        for (int jf = 0; jf < 2; ++jf)
          #pragma unroll
          for (int r = 0; r < 4; ++r)
            p += __expf(e[jf][ii][r] - mi[ii]);
        lacc[ii] += p;
      }
    }
  }

  // merge across the 4 lane-groups (disjoint j subsets, same i)
  #pragma unroll
  for (int ii = 0; ii < 4; ++ii){
    float l0 = lacc[ii];
    l0 += __shfl_xor(l0, 16);
    l0 += __shfl_xor(l0, 32);
    if (lane < 16) sll[w][16*ii + l15] = l0;
  }
  __syncthreads();
  // cross-wave merge (each wave covered a disjoint 1/4 of j)
  if (tid < 64)
    rowl[(long)b*N_ + i0 + tid] = sll[0][tid] + sll[1][tid] + sll[2][tid] + sll[3][tid];
}

// ---------------------------------------------------------------------------
// Pass 2, fat/thin restructure (round-3 form, proven 149 us):
//   per is-step: FAT = [ E'(is) MFMA+loads ; PV(is-1) MFMA+loads ; exp(is)->regs ]
//                -> barrier -> THIN = [ P' writes to pl ] -> barrier
// ---------------------------------------------------------------------------
__global__ __launch_bounds__(256, 2) void pass2_kernel(
    const unsigned short* __restrict__ q, const unsigned short* __restrict__ vT,
    const float* __restrict__ rowm, const float* __restrict__ rowl,
    const float* __restrict__ hf, unsigned short* __restrict__ dbf)
{
  extern __shared__ char smem[];
  unsigned short* qj = (unsigned short*)smem;   // [64][264]
  unsigned short* pl = qj + 64*264;             // [64][264]
  float* colsum = (float*)(pl + 64*264);        // [64]
  const int tid = threadIdx.x, lane = tid & 63, w = tid >> 6;
  const int lin = blockIdx.y * 32 + blockIdx.x;
  const int swz = (lin & 7) * 64 + (lin >> 3);  // XCD k -> 64 contiguous blocks
  const int b  = swz >> 5;
  const int j0 = (swz & 31) * 64;
  const unsigned short* qb = q  + (long)b*N_*C_;
  const unsigned short* vb = vT + (long)b*N_*C_;
  const float* mrow = rowm + (long)b*N_;
  const float* lrow = rowl + (long)b*N_;

  #pragma unroll
  for (int t = 0; t < 8; ++t){
    int idx = tid + t*256;
    int r = idx >> 5, c8 = (idx & 31) * 8;
    *(i32x4*)&qj[r*264 + c8] = *(const i32x4*)(qb + (long)(j0 + r)*256 + c8);
  }
  if (tid < 64) colsum[tid] = 0.f;
  __syncthreads();

  float cs[4][4];
  #pragma unroll
  for (int a = 0; a < 4; ++a)
    #pragma unroll
    for (int r = 0; r < 4; ++r) cs[a][r] = 0.f;
  f32x4 nm[4][4];
  #pragma unroll
  for (int a = 0; a < 4; ++a)
    #pragma unroll
    for (int c = 0; c < 4; ++c) nm[a][c] = f32x4{0.f,0.f,0.f,0.f};

  unsigned int pk[4][4][2];   // packed P' bf16 pairs [jf][f][r-pair]

  #pragma unroll 1
  for (int is = 0; is < 8; ++is){
    const int i0 = is * 256;
    const int iw = i0 + 64*w;       // this wave's i-slice

    // hoist m/l loads (independent of MFMA)
    float mi[4], ri[4];
    #pragma unroll
    for (int f = 0; f < 4; ++f){
      int ig = iw + 16*f + (lane&15);
      mi[f] = mrow[ig];
      ri[f] = __builtin_amdgcn_rcpf(lrow[ig]);
    }

    // ---- E'(is) ----
    f32x4 e[4][4];                  // [jf][if]
    #pragma unroll
    for (int a = 0; a < 4; ++a)
      #pragma unroll
      for (int f = 0; f < 4; ++f) e[a][f] = f32x4{0.f,0.f,0.f,0.f};
    #pragma unroll
    for (int kk = 0; kk < 8; ++kk){
      bf16x8 a[4], bb[4];
      #pragma unroll
      for (int jf = 0; jf < 4; ++jf)
        a[jf] = *(const bf16x8*)&qj[(16*jf + (lane&15))*264 + kk*32 + (lane>>4)*8];
      #pragma unroll
      for (int f = 0; f < 4; ++f)
        bb[f] = *(const bf16x8*)(qb + (long)(iw + 16*f + (lane&15))*256 + kk*32 + (lane>>4)*8);
      #pragma unroll
      for (int jf = 0; jf < 4; ++jf)
        #pragma unroll
        for (int f = 0; f < 4; ++f)
          e[jf][f] = MFMA(a[jf], bb[f], e[jf][f]);
    }

    // ---- PV(is-1): reads pl written in previous thin phase ----
    if (is > 0){
      const int ip = i0 - 256;
      #pragma unroll
      for (int kc = 0; kc < 8; ++kc){
        bf16x8 pa[4], vv[4];
        #pragma unroll
        for (int jf = 0; jf < 4; ++jf)
          pa[jf] = *(const bf16x8*)&pl[(16*jf + (lane&15))*264 + kc*32 + (lane>>4)*8];
        #pragma unroll
        for (int cf = 0; cf < 4; ++cf)
          vv[cf] = *(const bf16x8*)(vb + (long)(64*w + 16*cf + (lane&15))*2048 + ip + kc*32 + (lane>>4)*8);
        #pragma unroll
        for (int jf = 0; jf < 4; ++jf)
          #pragma unroll
          for (int cf = 0; cf < 4; ++cf)
            nm[jf][cf] = MFMA(pa[jf], vv[cf], nm[jf][cf]);
      }
    }

    // ---- exp(is) -> packed regs (VALU; co-schedules with PV MFMA) ----
    #pragma unroll
    for (int f = 0; f < 4; ++f){
      #pragma unroll
      for (int jf = 0; jf < 4; ++jf){
        #pragma unroll
        for (int rp = 0; rp < 2; ++rp){
          float p0 = __expf(e[jf][f][2*rp]   - mi[f]) * ri[f];
          float p1 = __expf(e[jf][f][2*rp+1] - mi[f]) * ri[f];
          cs[jf][2*rp]   += p0;
          cs[jf][2*rp+1] += p1;
          pk[jf][f][rp] = (unsigned int)f2b(p0) | ((unsigned int)f2b(p1) << 16);
        }
      }
    }

    __syncthreads();   // all PV(is-1) reads of pl done
    // ---- THIN: write P'(is) ----
    #pragma unroll
    for (int jf = 0; jf < 4; ++jf)
      #pragma unroll
      for (int f = 0; f < 4; ++f)
        #pragma unroll
        for (int rp = 0; rp < 2; ++rp){
          unsigned int v = pk[jf][f][rp];
          int col = 64*w + 16*f + (lane&15);
          pl[(16*jf + (lane>>4)*4 + 2*rp)*264 + col]     = (unsigned short)v;
          pl[(16*jf + (lane>>4)*4 + 2*rp+1)*264 + col]   = (unsigned short)(v >> 16);
        }
    __syncthreads();
  }

  // ---- PV(7) tail ----
  {
    const int ip = 7 * 256;
    #pragma unroll
    for (int kc = 0; kc < 8; ++kc){
      bf16x8 pa[4], vv[4];
      #pragma unroll
      for (int jf = 0; jf < 4; ++jf)
        pa[jf] = *(const bf16x8*)&pl[(16*jf + (lane&15))*264 + kc*32 + (lane>>4)*8];
      #pragma unroll
      for (int cf = 0; cf < 4; ++cf)
        vv[cf] = *(const bf16x8*)(vb + (long)(64*w + 16*cf + (lane&15))*2048 + ip + kc*32 + (lane>>4)*8);
      #pragma unroll
      for (int jf = 0; jf < 4; ++jf)
        #pragma unroll
        for (int cf = 0; cf < 4; ++cf)
          nm[jf][cf] = MFMA(pa[jf], vv[cf], nm[jf][cf]);
    }
  }

  // colsum: reduce across the 16-lane column group, then across waves via LDS atomics
  #pragma unroll
  for (int jf = 0; jf < 4; ++jf)
    #pragma unroll
    for (int r = 0; r < 4; ++r){
      float v = cs[jf][r];
      v += __shfl_xor(v, 1); v += __shfl_xor(v, 2);
      v += __shfl_xor(v, 4); v += __shfl_xor(v, 8);
      if ((lane & 15) == 0) atomicAdd(&colsum[16*jf + (lane>>4)*4 + r], v);
    }
  __syncthreads();

  #pragma unroll
  for (int jf = 0; jf < 4; ++jf)
    #pragma unroll
    for (int r = 0; r < 4; ++r){
      int jl = 16*jf + (lane>>4)*4 + r;
      float rcs = __builtin_amdgcn_rcpf(1e-9f + colsum[jl]);
      long rowg = (long)b*N_ + j0 + jl;
      #pragma unroll
      for (int cf = 0; cf < 4; ++cf){
        int c = 64*w + 16*cf + (lane&15);
        float xr = nm[jf][cf][r] * rcs;
        float d = hf[rowg*256 + c] - xr;
        dbf[rowg*256 + c] = f2b(d);
      }
    }
}

// ---------------------------------------------------------------------------
extern "C" void kernel_launch(void* const* d_in, const int* in_sizes, int n_in,
                              void* d_out, int out_size, void* d_ws, size_t ws_size,
                              hipStream_t stream)
{
  const float* x   = (const float*)d_in[0];
  const float* w1  = (const float*)d_in[1];
  const float* w2  = (const float*)d_in[2];
  const float* wqk = (const float*)d_in[3];
  const float* wv  = (const float*)d_in[4];
  const float* bv  = (const float*)d_in[5];
  const float* wt  = (const float*)d_in[6];
  const float* bt  = (const float*)d_in[7];
  const float* g1 = (const float*)d_in[8],  *b1 = (const float*)d_in[9];
  const float* m1 = (const float*)d_in[10], *v1 = (const float*)d_in[11];
  const float* g2 = (const float*)d_in[12], *b2 = (const float*)d_in[13];
  const float* m2 = (const float*)d_in[14], *v2 = (const float*)d_in[15];
  const float* g3 = (const float*)d_in[16], *b3 = (const float*)d_in[17];
  const float* m3 = (const float*)d_in[18], *v3 = (const float*)d_in[19];

  char* ws = (char*)d_ws;
  size_t off = 0;
  auto alloc = [&](size_t bytes)->char*{
    char* p = ws + off; off += (bytes + 255) & ~(size_t)255; return p;
  };
  unsigned short* w1b  = (unsigned short*)alloc(256*64*2);
  unsigned short* w2b  = (unsigned short*)alloc(256*256*2);
  unsigned short* wqkb = (unsigned short*)alloc(256*256*2);
  unsigned short* wvb  = (unsigned short*)alloc(256*256*2);
  unsigned short* wtb  = (unsigned short*)alloc(256*256*2);
  float* bias1 = (float*)alloc(256*4);
  float* bias2 = (float*)alloc(256*4);
  float* biasv = (float*)alloc(256*4);
  float* biast = (float*)alloc(256*4);
  unsigned short* h1_bf = (unsigned short*)alloc((size_t)BN_*C_*2);
  float*          h_f32 = (float*)alloc((size_t)BN_*C_*4);
  unsigned short* h_bf  = (unsigned short*)alloc((size_t)BN_*C_*2);
  unsigned short* q_bf  = (unsigned short*)alloc((size_t)BN_*C_*2);
  unsigned short* vT_bf = (unsigned short*)alloc((size_t)BN_*C_*2);
  float* rowm = (float*)alloc((size_t)BN_*4);
  float* rowl = (float*)alloc((size_t)BN_*4);
  unsigned short* d_bf  = (unsigned short*)alloc((size_t)BN_*C_*2);
  (void)ws_size; (void)in_sizes; (void)n_in; (void)out_size;

  hipFuncSetAttribute((const void*)&pass2_kernel,
                      hipFuncAttributeMaxDynamicSharedMemorySize, 67840);
  hipFuncSetAttribute((const void*)&wgemm<4,256>,
                      hipFuncAttributeMaxDynamicSharedMemorySize, 67840);

  prep_kernel<<<256, 256, 0, stream>>>(w1, w2, wqk, wv, bv, wt, bt,
      g1,b1,m1,v1, g2,b2,m2,v2, g3,b3,m3,v3,
      w1b, w2b, wqkb, wvb, wtb, bias1, bias2, biasv, biast);

  wgemm<0,64><<<512, 256, 46080, stream>>>(x, w1b, bias1, nullptr, h1_bf, nullptr);
  wgemm<1,256><<<512, 256, 46080, stream>>>(h1_bf, w2b, bias2, nullptr, h_bf, h_f32);
  wgemm<2,256><<<512, 256, 46080, stream>>>(h_bf, wqkb, nullptr, nullptr, q_bf, rowm);
  wgemm<3,256><<<512, 256, 46080, stream>>>(h_bf, wvb, biasv, nullptr, vT_bf, nullptr);

  pass1_kernel<<<dim3(32,16), 256, 0, stream>>>(q_bf, rowm, rowl);
  pass2_kernel<<<dim3(32,16), 256, 67840, stream>>>(q_bf, vT_bf, rowm, rowl, h_f32, d_bf);

  wgemm<4,256><<<512, 256, 67840, stream>>>(d_bf, wtb, biast, h_f32, d_out, nullptr);
}

// Round 8
// 347.957 us; speedup vs baseline: 1.2421x; 1.0365x over previous
//
#include <hip/hip_runtime.h>
#include <hip/hip_bf16.h>

// Problem constants
#define B_  16
#define N_  2048
#define C_  256
#define BN_ (B_*N_)

typedef __bf16 bf16x8 __attribute__((ext_vector_type(8)));
typedef float  f32x4  __attribute__((ext_vector_type(4)));
typedef int    i32x4  __attribute__((ext_vector_type(4)));

static __device__ __forceinline__ f32x4 MFMA(bf16x8 a, bf16x8 b, f32x4 c){
  return __builtin_amdgcn_mfma_f32_16x16x32_bf16(a, b, c, 0, 0, 0);
}
// f32 -> bf16 bits, round-to-nearest-even
static __device__ __forceinline__ unsigned short f2b(float f){
  unsigned int u = __float_as_uint(f);
  u += 0x7fffu + ((u >> 16) & 1u);
  return (unsigned short)(u >> 16);
}

// ---------------------------------------------------------------------------
// Prep: fold BN scale into bf16 weights, build f32 biases.
// ---------------------------------------------------------------------------
__global__ void prep_kernel(
    const float* __restrict__ w1, const float* __restrict__ w2,
    const float* __restrict__ wqk, const float* __restrict__ wv,
    const float* __restrict__ bv, const float* __restrict__ wt,
    const float* __restrict__ bt,
    const float* __restrict__ g1, const float* __restrict__ b1,
    const float* __restrict__ m1, const float* __restrict__ v1,
    const float* __restrict__ g2, const float* __restrict__ b2,
    const float* __restrict__ m2, const float* __restrict__ v2,
    const float* __restrict__ g3, const float* __restrict__ b3,
    const float* __restrict__ m3, const float* __restrict__ v3,
    unsigned short* __restrict__ w1b, unsigned short* __restrict__ w2b,
    unsigned short* __restrict__ wqkb, unsigned short* __restrict__ wvb,
    unsigned short* __restrict__ wtb,
    float* __restrict__ bias1, float* __restrict__ bias2,
    float* __restrict__ biasv, float* __restrict__ biast)
{
  const int d = blockIdx.x;
  const int c = threadIdx.x;
  const float s1 = g1[d] * rsqrtf(v1[d] + 1e-5f);
  const float s2 = g2[d] * rsqrtf(v2[d] + 1e-5f);
  const float s3 = g3[d] * rsqrtf(v3[d] + 1e-5f);
  if (c < 64) w1b[d*64 + c] = f2b(w1[d*64 + c] * s1);
  w2b[d*256 + c]  = f2b(w2[d*256 + c] * s2);
  wqkb[d*256 + c] = f2b(wqk[d*256 + c]);
  wvb[d*256 + c]  = f2b(wv[d*256 + c]);
  wtb[d*256 + c]  = f2b(wt[d*256 + c] * s3);
  if (c == 0){
    bias1[d] = b1[d] - m1[d]*s1;
    bias2[d] = b2[d] - m2[d]*s2;
    biasv[d] = bv[d];
    biast[d] = bt[d]*s3 + b3[d] - m3[d]*s3;
  }
}

// ---------------------------------------------------------------------------
// Generic "rows x weight^T" GEMM, Mtile=64 rows, all 256 out channels.
// MODE 2 additionally emits rowm[i] = sum_c q[i,c]^2 (= E[i,i], softmax shift).
// ---------------------------------------------------------------------------
template<int MODE, int K>
__global__ __launch_bounds__(256, 2) void wgemm(
    const void* __restrict__ inp, const unsigned short* __restrict__ wB,
    const float* __restrict__ bias, const float* __restrict__ hf32,
    void* __restrict__ out0, void* __restrict__ out1)
{
  extern __shared__ char smem[];
  unsigned short* Al = (unsigned short*)smem;               // [64][72]
  unsigned short* Bl = (unsigned short*)(smem + 64*72*2);   // [256][72]
  const int tid  = threadIdx.x;
  const int lane = tid & 63;
  const int w    = tid >> 6;
  const int wr   = w >> 1, wc = w & 1;
  const long row0 = (long)blockIdx.x * 64;

  f32x4 acc[2][8];
  #pragma unroll
  for (int m = 0; m < 2; ++m)
    #pragma unroll
    for (int n = 0; n < 8; ++n) acc[m][n] = f32x4{0.f,0.f,0.f,0.f};

  const int KS = K / 64;
  #pragma unroll 1
  for (int s = 0; s < KS; ++s){
    if (s) __syncthreads();
    if constexpr (MODE == 0){
      const float* xin = (const float*)inp;
      #pragma unroll
      for (int t = 0; t < 4; ++t){
        int idx = tid + t*256;              // 1024 chunks of 4 f32
        int r = idx >> 4, c4 = (idx & 15) * 4;
        float4 v = *(const float4*)(xin + (row0 + r)*K + c4);
        unsigned short* dst = &Al[r*72 + c4];
        dst[0]=f2b(v.x); dst[1]=f2b(v.y); dst[2]=f2b(v.z); dst[3]=f2b(v.w);
      }
    } else {
      const unsigned short* bin = (const unsigned short*)inp;
      #pragma unroll
      for (int t = 0; t < 2; ++t){
        int idx = tid + t*256;              // 512 chunks of 8 bf16
        int r = idx >> 3, c8 = (idx & 7) * 8;
        *(i32x4*)&Al[r*72 + c8] = *(const i32x4*)(bin + (row0 + r)*K + s*64 + c8);
      }
    }
    #pragma unroll
    for (int t = 0; t < 8; ++t){
      int idx = tid + t*256;                // 2048 chunks of 8 bf16
      int d = idx >> 3, c8 = (idx & 7) * 8;
      *(i32x4*)&Bl[d*72 + c8] = *(const i32x4*)(wB + d*K + s*64 + c8);
    }
    __syncthreads();
    #pragma unroll
    for (int kk = 0; kk < 2; ++kk){
      bf16x8 a[2], b[8];
      #pragma unroll
      for (int m = 0; m < 2; ++m)
        a[m] = *(const bf16x8*)&Al[(32*wr + 16*m + (lane&15))*72 + kk*32 + (lane>>4)*8];
      #pragma unroll
      for (int n = 0; n < 8; ++n)
        b[n] = *(const bf16x8*)&Bl[(128*wc + 16*n + (lane&15))*72 + kk*32 + (lane>>4)*8];
      #pragma unroll
      for (int m = 0; m < 2; ++m)
        #pragma unroll
        for (int n = 0; n < 8; ++n)
          acc[m][n] = MFMA(a[m], b[n], acc[m][n]);
    }
  }

  // ---- epilogues -------------------------------------------------------
  if constexpr (MODE <= 2){
    unsigned short* obf = (unsigned short*)out0;
    float* of = (float*)out1;
    float sq[2][4];
    #pragma unroll
    for (int m = 0; m < 2; ++m)
      #pragma unroll
      for (int r = 0; r < 4; ++r) sq[m][r] = 0.f;
    #pragma unroll
    for (int n = 0; n < 8; ++n){
      int col = 128*wc + 16*n + (lane&15);
      float bs = 0.f;
      if constexpr (MODE != 2) bs = bias[col];
      #pragma unroll
      for (int m = 0; m < 2; ++m){
        int rl = 32*wr + 16*m + (lane>>4)*4;
        #pragma unroll
        for (int r = 0; r < 4; ++r){
          float v = acc[m][n][r] + bs;
          if constexpr (MODE == 0 || MODE == 1) v = fmaxf(v, 0.f);
          obf[(row0 + rl + r)*256 + col] = f2b(v);
          if constexpr (MODE == 1) of[(row0 + rl + r)*256 + col] = v;
          if constexpr (MODE == 2) sq[m][r] += v*v;
        }
      }
    }
    if constexpr (MODE == 2){
      #pragma unroll
      for (int m = 0; m < 2; ++m)
        #pragma unroll
        for (int r = 0; r < 4; ++r){
          float s = sq[m][r];
          s += __shfl_xor(s, 1); s += __shfl_xor(s, 2);
          s += __shfl_xor(s, 4); s += __shfl_xor(s, 8);
          sq[m][r] = s;
        }
      __syncthreads();
      float* ssq = (float*)smem;
      if (tid < 64) ssq[tid] = 0.f;
      __syncthreads();
      if ((lane & 15) == 0){
        #pragma unroll
        for (int m = 0; m < 2; ++m)
          #pragma unroll
          for (int r = 0; r < 4; ++r)
            atomicAdd(&ssq[32*wr + 16*m + (lane>>4)*4 + r], sq[m][r]);
      }
      __syncthreads();
      if (tid < 64) ((float*)out1)[row0 + tid] = ssq[tid];
    }
  } else if constexpr (MODE == 3){
    __syncthreads();
    unsigned short* Vl = (unsigned short*)smem;   // [64][264]
    #pragma unroll
    for (int n = 0; n < 8; ++n){
      int col = 128*wc + 16*n + (lane&15);
      float bs = bias[col];
      #pragma unroll
      for (int m = 0; m < 2; ++m){
        int rl = 32*wr + 16*m + (lane>>4)*4;
        #pragma unroll
        for (int r = 0; r < 4; ++r)
          Vl[(rl + r)*264 + col] = f2b(acc[m][n][r] + bs);
      }
    }
    __syncthreads();
    long b = row0 >> 11;
    int  n0 = (int)(row0 & 2047);
    unsigned short* vt = (unsigned short*)out0 + b*(256L*2048);
    #pragma unroll 1
    for (int cc = 0; cc < 64; ++cc){
      int c = 64*w + cc;
      vt[(long)c*2048 + n0 + lane] = Vl[lane*264 + c];
    }
  } else {  // MODE 4
    __syncthreads();
    float* Ol = (float*)smem;                    // [64][265]
    #pragma unroll
    for (int n = 0; n < 8; ++n){
      int col = 128*wc + 16*n + (lane&15);
      float bs = bias[col];
      #pragma unroll
      for (int m = 0; m < 2; ++m){
        int rl = 32*wr + 16*m + (lane>>4)*4;
        #pragma unroll
        for (int r = 0; r < 4; ++r){
          float t = fmaxf(acc[m][n][r] + bs, 0.f);
          float h = hf32[(row0 + rl + r)*256 + col];
          Ol[(rl + r)*265 + col] = h + t;
        }
      }
    }
    __syncthreads();
    long b = row0 >> 11;
    int  n0 = (int)(row0 & 2047);
    float* op = (float*)out0 + b*(256L*2048);
    #pragma unroll 1
    for (int cc = 0; cc < 64; ++cc){
      int c = 64*w + cc;
      op[(long)c*2048 + n0 + lane] = Ol[lane*265 + c];
    }
  }
}

// ---------------------------------------------------------------------------
// Pass 1 (l-only, STAGED): rowl[i] = sum_j exp(E[i,j] - rowm[i]).
// 2-phase double-buffered j-stream via global_load_lds (T3-lite):
//  - jbuf[2][32 rows][512B] LINEAR; global source col pre-XOR-swizzled
//    (byte ^= (row&7)<<4), ds_read applies the same XOR -> optimal bank use.
//  - wave w's q_i B-fragments (rows i0+16w+l15) hoisted to 8 regs (invariant).
//  - stage(next) issued before compute(cur); __syncthreads' vmcnt drain is
//    the phase boundary. Per-lane state ~75 VGPR -> no spill at (256,4).
// ---------------------------------------------------------------------------
__global__ __launch_bounds__(256, 4) void pass1_kernel(
    const unsigned short* __restrict__ q,
    const float* __restrict__ rowm, float* __restrict__ rowl)
{
  __shared__ unsigned short jbuf[2][32*256];   // 2 x 16KB, linear
  const int tid = threadIdx.x, lane = tid & 63, w = tid >> 6;
  const int l15 = lane & 15, hi = lane >> 4;
  const int lin = blockIdx.y * 32 + blockIdx.x;
  const int swz = (lin & 7) * 64 + (lin >> 3);   // XCD k -> 64 contiguous blocks
  const int b  = swz >> 5;
  const int i0 = (swz & 31) * 64;
  const unsigned short* qb = q + (long)b*N_*C_;

  // hoisted loop-invariant q_i fragments for this wave's 16 i-rows
  bf16x8 bqi[8];
  #pragma unroll
  for (int kk = 0; kk < 8; ++kk)
    bqi[kk] = *(const bf16x8*)(qb + (long)(i0 + 16*w + l15)*256 + kk*32 + hi*8);
  const float mi = rowm[(long)b*N_ + i0 + 16*w + l15];
  float lacc = 0.f;

  const char* qbb = (const char*)qb;

  // stage 32 j-rows (16KB) of chunk js into jbuf[sel]
  auto stage = [&](int sel, int js){
    const char* src = qbb + (size_t)js * (32*512);
    #pragma unroll
    for (int t = 0; t < 4; ++t){
      int idx = t*256 + tid;
      int row = idx >> 5, c16 = idx & 31;
      const char* g = src + (size_t)row*512 + ((c16*16) ^ ((row & 7) << 4));
#if __has_builtin(__builtin_amdgcn_global_load_lds)
      char* l = (char*)&jbuf[sel][0] + (size_t)(t*256 + w*64)*16;  // wave-uniform base
      __builtin_amdgcn_global_load_lds(
          (const __attribute__((address_space(1))) void*)g,
          (__attribute__((address_space(3))) void*)l, 16, 0, 0);
#else
      *(i32x4*)((char*)&jbuf[sel][0] + (size_t)idx*16) = *(const i32x4*)g;
#endif
    }
  };

  stage(0, 0);
  __syncthreads();

  #pragma unroll 1
  for (int js = 0; js < 64; ++js){
    const int cur = js & 1;
    if (js < 63) stage(cur ^ 1, js + 1);   // DMA overlaps compute below

    const char* jb = (const char*)&jbuf[cur][0];
    const int sx = (l15 & 7) << 4;
    f32x4 e0 = f32x4{0.f,0.f,0.f,0.f};
    f32x4 e1 = f32x4{0.f,0.f,0.f,0.f};
    #pragma unroll
    for (int kk = 0; kk < 8; ++kk){
      int colb = kk*64 + hi*16;
      bf16x8 a0 = *(const bf16x8*)(jb + (size_t)l15*512        + (colb ^ sx));
      bf16x8 a1 = *(const bf16x8*)(jb + (size_t)(16+l15)*512   + (colb ^ sx));
      e0 = MFMA(a0, bqi[kk], e0);
      e1 = MFMA(a1, bqi[kk], e1);
    }
    float p = __expf(e0[0]-mi) + __expf(e0[1]-mi) + __expf(e0[2]-mi) + __expf(e0[3]-mi)
            + __expf(e1[0]-mi) + __expf(e1[1]-mi) + __expf(e1[2]-mi) + __expf(e1[3]-mi);
    lacc += p;

    __syncthreads();   // drains this wave's gload_lds (vmcnt) + cur fully read
  }

  // lanes differ only in hi for the same i -> sum the 4 hi partials
  lacc += __shfl_xor(lacc, 16);
  lacc += __shfl_xor(lacc, 32);
  if (lane < 16)
    rowl[(long)b*N_ + i0 + 16*w + l15] = lacc;
}

// ---------------------------------------------------------------------------
// Pass 2, fat/thin restructure (round-3 form, proven ~150 us):
//   per is-step: FAT = [ E'(is) MFMA+loads ; PV(is-1) MFMA+loads ; exp(is)->regs ]
//                -> barrier -> THIN = [ P' writes to pl ] -> barrier
// ---------------------------------------------------------------------------
__global__ __launch_bounds__(256, 2) void pass2_kernel(
    const unsigned short* __restrict__ q, const unsigned short* __restrict__ vT,
    const float* __restrict__ rowm, const float* __restrict__ rowl,
    const float* __restrict__ hf, unsigned short* __restrict__ dbf)
{
  extern __shared__ char smem[];
  unsigned short* qj = (unsigned short*)smem;   // [64][264]
  unsigned short* pl = qj + 64*264;             // [64][264]
  float* colsum = (float*)(pl + 64*264);        // [64]
  const int tid = threadIdx.x, lane = tid & 63, w = tid >> 6;
  const int lin = blockIdx.y * 32 + blockIdx.x;
  const int swz = (lin & 7) * 64 + (lin >> 3);  // XCD k -> 64 contiguous blocks
  const int b  = swz >> 5;
  const int j0 = (swz & 31) * 64;
  const unsigned short* qb = q  + (long)b*N_*C_;
  const unsigned short* vb = vT + (long)b*N_*C_;
  const float* mrow = rowm + (long)b*N_;
  const float* lrow = rowl + (long)b*N_;

  #pragma unroll
  for (int t = 0; t < 8; ++t){
    int idx = tid + t*256;
    int r = idx >> 5, c8 = (idx & 31) * 8;
    *(i32x4*)&qj[r*264 + c8] = *(const i32x4*)(qb + (long)(j0 + r)*256 + c8);
  }
  if (tid < 64) colsum[tid] = 0.f;
  __syncthreads();

  float cs[4][4];
  #pragma unroll
  for (int a = 0; a < 4; ++a)
    #pragma unroll
    for (int r = 0; r < 4; ++r) cs[a][r] = 0.f;
  f32x4 nm[4][4];
  #pragma unroll
  for (int a = 0; a < 4; ++a)
    #pragma unroll
    for (int c = 0; c < 4; ++c) nm[a][c] = f32x4{0.f,0.f,0.f,0.f};

  unsigned int pk[4][4][2];   // packed P' bf16 pairs [jf][f][r-pair]

  #pragma unroll 1
  for (int is = 0; is < 8; ++is){
    const int i0 = is * 256;
    const int iw = i0 + 64*w;       // this wave's i-slice

    // hoist m/l loads (independent of MFMA)
    float mi[4], ri[4];
    #pragma unroll
    for (int f = 0; f < 4; ++f){
      int ig = iw + 16*f + (lane&15);
      mi[f] = mrow[ig];
      ri[f] = __builtin_amdgcn_rcpf(lrow[ig]);
    }

    // ---- E'(is) ----
    f32x4 e[4][4];                  // [jf][if]
    #pragma unroll
    for (int a = 0; a < 4; ++a)
      #pragma unroll
      for (int f = 0; f < 4; ++f) e[a][f] = f32x4{0.f,0.f,0.f,0.f};
    #pragma unroll
    for (int kk = 0; kk < 8; ++kk){
      bf16x8 a[4], bb[4];
      #pragma unroll
      for (int jf = 0; jf < 4; ++jf)
        a[jf] = *(const bf16x8*)&qj[(16*jf + (lane&15))*264 + kk*32 + (lane>>4)*8];
      #pragma unroll
      for (int f = 0; f < 4; ++f)
        bb[f] = *(const bf16x8*)(qb + (long)(iw + 16*f + (lane&15))*256 + kk*32 + (lane>>4)*8);
      #pragma unroll
      for (int jf = 0; jf < 4; ++jf)
        #pragma unroll
        for (int f = 0; f < 4; ++f)
          e[jf][f] = MFMA(a[jf], bb[f], e[jf][f]);
    }

    // ---- PV(is-1): reads pl written in previous thin phase ----
    if (is > 0){
      const int ip = i0 - 256;
      #pragma unroll
      for (int kc = 0; kc < 8; ++kc){
        bf16x8 pa[4], vv[4];
        #pragma unroll
        for (int jf = 0; jf < 4; ++jf)
          pa[jf] = *(const bf16x8*)&pl[(16*jf + (lane&15))*264 + kc*32 + (lane>>4)*8];
        #pragma unroll
        for (int cf = 0; cf < 4; ++cf)
          vv[cf] = *(const bf16x8*)(vb + (long)(64*w + 16*cf + (lane&15))*2048 + ip + kc*32 + (lane>>4)*8);
        #pragma unroll
        for (int jf = 0; jf < 4; ++jf)
          #pragma unroll
          for (int cf = 0; cf < 4; ++cf)
            nm[jf][cf] = MFMA(pa[jf], vv[cf], nm[jf][cf]);
      }
    }

    // ---- exp(is) -> packed regs (VALU; co-schedules with PV MFMA) ----
    #pragma unroll
    for (int f = 0; f < 4; ++f){
      #pragma unroll
      for (int jf = 0; jf < 4; ++jf){
        #pragma unroll
        for (int rp = 0; rp < 2; ++rp){
          float p0 = __expf(e[jf][f][2*rp]   - mi[f]) * ri[f];
          float p1 = __expf(e[jf][f][2*rp+1] - mi[f]) * ri[f];
          cs[jf][2*rp]   += p0;
          cs[jf][2*rp+1] += p1;
          pk[jf][f][rp] = (unsigned int)f2b(p0) | ((unsigned int)f2b(p1) << 16);
        }
      }
    }

    __syncthreads();   // all PV(is-1) reads of pl done
    // ---- THIN: write P'(is) ----
    #pragma unroll
    for (int jf = 0; jf < 4; ++jf)
      #pragma unroll
      for (int f = 0; f < 4; ++f)
        #pragma unroll
        for (int rp = 0; rp < 2; ++rp){
          unsigned int v = pk[jf][f][rp];
          int col = 64*w + 16*f + (lane&15);
          pl[(16*jf + (lane>>4)*4 + 2*rp)*264 + col]     = (unsigned short)v;
          pl[(16*jf + (lane>>4)*4 + 2*rp+1)*264 + col]   = (unsigned short)(v >> 16);
        }
    __syncthreads();
  }

  // ---- PV(7) tail ----
  {
    const int ip = 7 * 256;
    #pragma unroll
    for (int kc = 0; kc < 8; ++kc){
      bf16x8 pa[4], vv[4];
      #pragma unroll
      for (int jf = 0; jf < 4; ++jf)
        pa[jf] = *(const bf16x8*)&pl[(16*jf + (lane&15))*264 + kc*32 + (lane>>4)*8];
      #pragma unroll
      for (int cf = 0; cf < 4; ++cf)
        vv[cf] = *(const bf16x8*)(vb + (long)(64*w + 16*cf + (lane&15))*2048 + ip + kc*32 + (lane>>4)*8);
      #pragma unroll
      for (int jf = 0; jf < 4; ++jf)
        #pragma unroll
        for (int cf = 0; cf < 4; ++cf)
          nm[jf][cf] = MFMA(pa[jf], vv[cf], nm[jf][cf]);
    }
  }

  // colsum: reduce across the 16-lane column group, then across waves via LDS atomics
  #pragma unroll
  for (int jf = 0; jf < 4; ++jf)
    #pragma unroll
    for (int r = 0; r < 4; ++r){
      float v = cs[jf][r];
      v += __shfl_xor(v, 1); v += __shfl_xor(v, 2);
      v += __shfl_xor(v, 4); v += __shfl_xor(v, 8);
      if ((lane & 15) == 0) atomicAdd(&colsum[16*jf + (lane>>4)*4 + r], v);
    }
  __syncthreads();

  #pragma unroll
  for (int jf = 0; jf < 4; ++jf)
    #pragma unroll
    for (int r = 0; r < 4; ++r){
      int jl = 16*jf + (lane>>4)*4 + r;
      float rcs = __builtin_amdgcn_rcpf(1e-9f + colsum[jl]);
      long rowg = (long)b*N_ + j0 + jl;
      #pragma unroll
      for (int cf = 0; cf < 4; ++cf){
        int c = 64*w + 16*cf + (lane&15);
        float xr = nm[jf][cf][r] * rcs;
        float d = hf[rowg*256 + c] - xr;
        dbf[rowg*256 + c] = f2b(d);
      }
    }
}

// ---------------------------------------------------------------------------
extern "C" void kernel_launch(void* const* d_in, const int* in_sizes, int n_in,
                              void* d_out, int out_size, void* d_ws, size_t ws_size,
                              hipStream_t stream)
{
  const float* x   = (const float*)d_in[0];
  const float* w1  = (const float*)d_in[1];
  const float* w2  = (const float*)d_in[2];
  const float* wqk = (const float*)d_in[3];
  const float* wv  = (const float*)d_in[4];
  const float* bv  = (const float*)d_in[5];
  const float* wt  = (const float*)d_in[6];
  const float* bt  = (const float*)d_in[7];
  const float* g1 = (const float*)d_in[8],  *b1 = (const float*)d_in[9];
  const float* m1 = (const float*)d_in[10], *v1 = (const float*)d_in[11];
  const float* g2 = (const float*)d_in[12], *b2 = (const float*)d_in[13];
  const float* m2 = (const float*)d_in[14], *v2 = (const float*)d_in[15];
  const float* g3 = (const float*)d_in[16], *b3 = (const float*)d_in[17];
  const float* m3 = (const float*)d_in[18], *v3 = (const float*)d_in[19];

  char* ws = (char*)d_ws;
  size_t off = 0;
  auto alloc = [&](size_t bytes)->char*{
    char* p = ws + off; off += (bytes + 255) & ~(size_t)255; return p;
  };
  unsigned short* w1b  = (unsigned short*)alloc(256*64*2);
  unsigned short* w2b  = (unsigned short*)alloc(256*256*2);
  unsigned short* wqkb = (unsigned short*)alloc(256*256*2);
  unsigned short* wvb  = (unsigned short*)alloc(256*256*2);
  unsigned short* wtb  = (unsigned short*)alloc(256*256*2);
  float* bias1 = (float*)alloc(256*4);
  float* bias2 = (float*)alloc(256*4);
  float* biasv = (float*)alloc(256*4);
  float* biast = (float*)alloc(256*4);
  unsigned short* h1_bf = (unsigned short*)alloc((size_t)BN_*C_*2);
  float*          h_f32 = (float*)alloc((size_t)BN_*C_*4);
  unsigned short* h_bf  = (unsigned short*)alloc((size_t)BN_*C_*2);
  unsigned short* q_bf  = (unsigned short*)alloc((size_t)BN_*C_*2);
  unsigned short* vT_bf = (unsigned short*)alloc((size_t)BN_*C_*2);
  float* rowm = (float*)alloc((size_t)BN_*4);
  float* rowl = (float*)alloc((size_t)BN_*4);
  unsigned short* d_bf  = (unsigned short*)alloc((size_t)BN_*C_*2);
  (void)ws_size; (void)in_sizes; (void)n_in; (void)out_size;

  hipFuncSetAttribute((const void*)&pass2_kernel,
                      hipFuncAttributeMaxDynamicSharedMemorySize, 67840);
  hipFuncSetAttribute((const void*)&wgemm<4,256>,
                      hipFuncAttributeMaxDynamicSharedMemorySize, 67840);

  prep_kernel<<<256, 256, 0, stream>>>(w1, w2, wqk, wv, bv, wt, bt,
      g1,b1,m1,v1, g2,b2,m2,v2, g3,b3,m3,v3,
      w1b, w2b, wqkb, wvb, wtb, bias1, bias2, biasv, biast);

  wgemm<0,64><<<512, 256, 46080, stream>>>(x, w1b, bias1, nullptr, h1_bf, nullptr);
  wgemm<1,256><<<512, 256, 46080, stream>>>(h1_bf, w2b, bias2, nullptr, h_bf, h_f32);
  wgemm<2,256><<<512, 256, 46080, stream>>>(h_bf, wqkb, nullptr, nullptr, q_bf, rowm);
  wgemm<3,256><<<512, 256, 46080, stream>>>(h_bf, wvb, biasv, nullptr, vT_bf, nullptr);

  pass1_kernel<<<dim3(32,16), 256, 0, stream>>>(q_bf, rowm, rowl);
  pass2_kernel<<<dim3(32,16), 256, 67840, stream>>>(q_bf, vT_bf, rowm, rowl, h_f32, d_bf);

  wgemm<4,256><<<512, 256, 67840, stream>>>(d_bf, wtb, biast, h_f32, d_out, nullptr);
}